// Round 1
// baseline (20040.375 us; speedup 1.0000x reference)
//
#include <hip/hip_runtime.h>
#include <hip/hip_cooperative_groups.h>
#include <math.h>
#include <cstdint>

namespace cg = cooperative_groups;

#define BB 32
#define LL 256
#define TT 8192     // B*L
#define DIN 256
#define WEDm 200
#define PEDm 56
#define HH 512
#define G4 2048
#define MM 1024
#define EE 100
#define NTAGS 16

// ---------------- K1: embedding concat ----------------
__global__ void k_embed(const int* __restrict__ word, const int* __restrict__ posi,
                        const float* __restrict__ wemb, const float* __restrict__ pemb,
                        float* __restrict__ X) {
  int t = blockIdx.x;
  int c = threadIdx.x * 4;
  float4 v;
  if (c < WEDm) {
    int w = word[t];
    v = *(const float4*)(wemb + (size_t)w * WEDm + c);
  } else {
    int p = posi[t];
    v = *(const float4*)(pemb + (size_t)p * PEDm + (c - WEDm));
  }
  *(float4*)(X + (size_t)t * DIN + c) = v;
}

// ---------------- K2: C = A@W + bias (f32 tiled) ----------------
__global__ __launch_bounds__(256) void k_gemm_bias(const float* __restrict__ A,
    const float* __restrict__ W, const float* __restrict__ bias,
    float* __restrict__ C, int Mm, int Nn, int Kk) {
  __shared__ float As[16][68];
  __shared__ float Bs[16][64];
  int tid = threadIdx.x;
  int tx = tid & 15, ty = tid >> 4;
  int row0 = blockIdx.y * 64, col0 = blockIdx.x * 64;
  float acc[4][4] = {};
  for (int k0 = 0; k0 < Kk; k0 += 16) {
    int r = tid >> 2, c = (tid & 3) * 4;
    float4 av = *(const float4*)(A + (size_t)(row0 + r) * Kk + k0 + c);
    As[c + 0][r] = av.x; As[c + 1][r] = av.y; As[c + 2][r] = av.z; As[c + 3][r] = av.w;
    int r2 = tid >> 4, c2 = (tid & 15) * 4;
    float4 bv = *(const float4*)(W + (size_t)(k0 + r2) * Nn + col0 + c2);
    *(float4*)(&Bs[r2][c2]) = bv;
    __syncthreads();
#pragma unroll
    for (int kk = 0; kk < 16; ++kk) {
      float4 a4 = *(const float4*)(&As[kk][ty * 4]);
      float4 b4 = *(const float4*)(&Bs[kk][tx * 4]);
      float a[4] = {a4.x, a4.y, a4.z, a4.w};
      float b[4] = {b4.x, b4.y, b4.z, b4.w};
#pragma unroll
      for (int i = 0; i < 4; ++i)
#pragma unroll
        for (int j = 0; j < 4; ++j)
          acc[i][j] += a[i] * b[j];
    }
    __syncthreads();
  }
#pragma unroll
  for (int i = 0; i < 4; ++i) {
    int row = row0 + ty * 4 + i;
#pragma unroll
    for (int j = 0; j < 4; ++j) {
      int col = col0 + tx * 4 + j;
      C[(size_t)row * Nn + col] = acc[i][j] + bias[col];
    }
  }
}

// ---------------- K3: cooperative bidirectional LSTM ----------------
// 256 WGs x 512 threads. WG w: dir = w>>7, owns 4 hidden units (16 gate cols).
// Wh slice resident in LDS; h double-buffered in global; grid.sync per step.
__global__ __launch_bounds__(512) void k_lstm(const float* __restrict__ Whf,
    const float* __restrict__ Whb, const float* __restrict__ GXfp,
    const float* __restrict__ GXbp, const float* __restrict__ maskp,
    float* __restrict__ Hbuf, float* __restrict__ ctx) {
  __shared__ float Whs[16][516];   // [local col][k], padded stride vs bank conflicts
  __shared__ float Hs[32][516];    // [batch][k]
  __shared__ float pre[32][16];
  __shared__ float cst[128];       // c-state per (batch, unit)
  cg::grid_group grid = cg::this_grid();
  int wg = blockIdx.x;
  int dir = wg >> 7;
  int grp = wg & 127;
  int j0 = grp * 4;
  int tid = threadIdx.x;
  const float* Wh = dir ? Whb : Whf;
  const float* GX = dir ? GXbp : GXfp;
  float* Hb = Hbuf + (size_t)dir * 2 * BB * HH;
  {
    int c = tid & 15;
    int u = c & 3, q = c >> 2;
    int gcol = q * HH + j0 + u;
    for (int k = tid >> 4; k < HH; k += 32)
      Whs[c][k] = Wh[(size_t)k * G4 + gcol];
  }
  if (tid < 128) {
    cst[tid] = 0.f;
    int b = tid >> 2, u = tid & 3;
    Hb[(size_t)b * HH + j0 + u] = 0.f;   // zero parity-0 h
  }
  grid.sync();
  int par = 0;
  for (int s = 0; s < LL; ++s) {
    int t = dir ? (LL - 1 - s) : s;
    const float* hsrc = Hb + (size_t)par * BB * HH;
#pragma unroll
    for (int i = 0; i < 8; ++i) {          // stage h[32][512] into LDS
      int f = i * 2048 + tid * 4;
      float4 v = *(const float4*)(hsrc + f);
      int b = f >> 9, k = f & 511;
      *(float4*)(&Hs[b][k]) = v;
    }
    __syncthreads();
    {
      int b = tid >> 4, c = tid & 15;
      int u = c & 3, q = c >> 2;
      int gcol = q * HH + j0 + u;
      float acc = 0.f;
#pragma unroll 8
      for (int k = 0; k < HH; k += 4) {
        float4 h4 = *(const float4*)(&Hs[b][k]);
        float4 w4 = *(const float4*)(&Whs[c][k]);
        acc += h4.x * w4.x + h4.y * w4.y + h4.z * w4.z + h4.w * w4.w;
      }
      acc += GX[((size_t)(b * LL + t)) * G4 + gcol];
      pre[b][c] = acc;
    }
    __syncthreads();
    if (tid < 128) {
      int bb = tid >> 2, uu = tid & 3;
      float xi = pre[bb][uu];
      float xf = pre[bb][4 + uu];
      float xg = pre[bb][8 + uu];
      float xo = pre[bb][12 + uu];
      float gi = 1.f / (1.f + expf(-xi));
      float gf = 1.f / (1.f + expf(-xf));
      float gg = tanhf(xg);
      float go = 1.f / (1.f + expf(-xo));
      float cold = cst[tid];
      float cnew = gf * cold + gi * gg;
      float hnew = go * tanhf(cnew);
      float m = maskp[bb * LL + t];
      float hold = Hs[bb][j0 + uu];
      float hn = hnew * m + hold * (1.f - m);
      float cn = cnew * m + cold * (1.f - m);
      cst[tid] = cn;
      Hb[(size_t)(par ^ 1) * BB * HH + bb * HH + j0 + uu] = hn;
      ctx[((size_t)(bb * LL + t)) * (2 * HH) + dir * HH + j0 + uu] = hn;
    }
    __threadfence();
    grid.sync();
    par ^= 1;
  }
}

// ---------------- K4: tag histogram + stable compaction ----------------
__global__ void k_zero16(int* counts) { if (threadIdx.x < 16) counts[threadIdx.x] = 0; }

__global__ void k_count(const int* __restrict__ posi, int* __restrict__ counts) {
  int t = blockIdx.x * 256 + threadIdx.x;
  if (t < TT) atomicAdd(&counts[posi[t]], 1);
}

__global__ void k_prefix(const int* __restrict__ counts, int* __restrict__ offs) {
  if (threadIdx.x == 0) {
    int a = 0;
    for (int p = 0; p < NTAGS; ++p) { offs[p] = a; a += counts[p]; }
    offs[NTAGS] = a;
  }
}

__global__ __launch_bounds__(256) void k_compact(const int* __restrict__ posi,
    const int* __restrict__ offs, int* __restrict__ idxlist) {
  int p = blockIdx.x, tid = threadIdx.x;
  __shared__ int sc[256];
  __shared__ int sbase;
  if (tid == 0) sbase = offs[p];
  __syncthreads();
  for (int c0 = 0; c0 < TT; c0 += 256) {
    int t = c0 + tid;
    int f = (posi[t] == p) ? 1 : 0;
    int v = f;
    sc[tid] = v;
    __syncthreads();
    for (int o = 1; o < 256; o <<= 1) {
      int add = (tid >= o) ? sc[tid - o] : 0;
      __syncthreads();
      v += add;
      sc[tid] = v;
      __syncthreads();
    }
    int total = sc[255];
    int base = sbase;
    if (f) idxlist[base + v - 1] = t;
    __syncthreads();
    if (tid == 0) sbase = base + total;
    __syncthreads();
  }
}

// ---------------- K4b: gather per-tag psr rows ----------------
__global__ void k_ptbl(const int* __restrict__ wtbl, const float* __restrict__ psrw,
                       float* __restrict__ Ptbl) {
  int i = blockIdx.x * 256 + threadIdx.x;
  int total = NTAGS * MM * EE;
  for (; i < total; i += gridDim.x * 256) {
    int p = i / (MM * EE);
    int rem = i - p * (MM * EE);
    int r = rem / EE;
    int e = rem - r * EE;
    Ptbl[i] = psrw[(size_t)wtbl[p * MM + r] * EE + e];
  }
}

// ---------------- K5: grouped decoder GEMM Z[tok] = ctx[tok]@dec_W[p] + dec_b[p] ----------------
__global__ __launch_bounds__(256) void k_decgemm(const float* __restrict__ ctxb,
    const float* __restrict__ decW, const float* __restrict__ decb,
    const int* __restrict__ counts, const int* __restrict__ offs,
    const int* __restrict__ idxlist, float* __restrict__ Z) {
  int p = blockIdx.z;
  int n = counts[p];
  int r0 = blockIdx.y * 64;
  if (r0 >= n) return;
  int col0 = blockIdx.x * 64;
  __shared__ float As[16][68];
  __shared__ float Bs[16][64];
  __shared__ int rows[64];
  int tid = threadIdx.x;
  if (tid < 64) {
    int r = r0 + tid;
    rows[tid] = idxlist[offs[p] + (r < n ? r : 0)];
  }
  __syncthreads();
  const float* W = decW + (size_t)p * MM * MM;
  float acc[4][4] = {};
  for (int k0 = 0; k0 < MM; k0 += 16) {
    int r = tid >> 2, c = (tid & 3) * 4;
    float4 av = *(const float4*)(ctxb + (size_t)rows[r] * MM + k0 + c);
    As[c + 0][r] = av.x; As[c + 1][r] = av.y; As[c + 2][r] = av.z; As[c + 3][r] = av.w;
    int r2 = tid >> 4, c2 = (tid & 15) * 4;
    float4 bv = *(const float4*)(W + (size_t)(k0 + r2) * MM + col0 + c2);
    *(float4*)(&Bs[r2][c2]) = bv;
    __syncthreads();
#pragma unroll
    for (int kk = 0; kk < 16; ++kk) {
      float4 a4 = *(const float4*)(&As[kk][(tid >> 4) * 4]);
      float4 b4 = *(const float4*)(&Bs[kk][(tid & 15) * 4]);
      float a[4] = {a4.x, a4.y, a4.z, a4.w};
      float b[4] = {b4.x, b4.y, b4.z, b4.w};
#pragma unroll
      for (int i = 0; i < 4; ++i)
#pragma unroll
        for (int j = 0; j < 4; ++j)
          acc[i][j] += a[i] * b[j];
    }
    __syncthreads();
  }
  int tx = tid & 15, ty = tid >> 4;
#pragma unroll
  for (int i = 0; i < 4; ++i) {
    int r = r0 + ty * 4 + i;
    if (r < n) {
      int tok = rows[ty * 4 + i];
#pragma unroll
      for (int j = 0; j < 4; ++j) {
        int col = col0 + tx * 4 + j;
        Z[(size_t)tok * MM + col] = acc[i][j] + decb[p * MM + col];
      }
    }
  }
}

// ---------------- K6: per-token softmax / entropy / gumbel argmax ----------------
__global__ __launch_bounds__(256) void k_softmax(
    const float* __restrict__ Z, const float* __restrict__ gum,
    const int* __restrict__ posi, const int* __restrict__ wflat,
    const int* __restrict__ wtbl, float* __restrict__ SPT,
    float* __restrict__ rowent, int* __restrict__ avoidb,
    float* __restrict__ out_word, float* __restrict__ out_mask,
    float* __restrict__ out_pri) {
  __shared__ float red[256];
  __shared__ float redv[256];
  __shared__ int redi[256];
  int t = blockIdx.x, tid = threadIdx.x;
  float z[4];
#pragma unroll
  for (int i = 0; i < 4; ++i) z[i] = Z[(size_t)t * MM + tid + 256 * i];
  float mx = fmaxf(fmaxf(z[0], z[1]), fmaxf(z[2], z[3]));
  red[tid] = mx; __syncthreads();
  for (int o = 128; o > 0; o >>= 1) { if (tid < o) red[tid] = fmaxf(red[tid], red[tid + o]); __syncthreads(); }
  mx = red[0]; __syncthreads();
  float se = 0.f;
#pragma unroll
  for (int i = 0; i < 4; ++i) se += expf(z[i] - mx);
  red[tid] = se; __syncthreads();
  for (int o = 128; o > 0; o >>= 1) { if (tid < o) red[tid] += red[tid + o]; __syncthreads(); }
  float lse = logf(red[0]); __syncthreads();
  float lp[4]; float ent = 0.f;
#pragma unroll
  for (int i = 0; i < 4; ++i) { lp[i] = z[i] - mx - lse; ent -= lp[i] * expf(lp[i]); }
  red[tid] = ent; __syncthreads();
  for (int o = 128; o > 0; o >>= 1) { if (tid < o) red[tid] += red[tid + o]; __syncthreads(); }
  float enttot = red[0]; __syncthreads();
  float y[4];
#pragma unroll
  for (int i = 0; i < 4; ++i) {
    float u = gum[(size_t)t * MM + tid + 256 * i];
    float g = -logf(-logf(u + 1e-10f) + 1e-10f);
    y[i] = lp[i] + g;
  }
  float bv = y[0]; int bi = tid;
#pragma unroll
  for (int i = 1; i < 4; ++i) { int j = tid + 256 * i; if (y[i] > bv) { bv = y[i]; bi = j; } }
  redv[tid] = bv; redi[tid] = bi; __syncthreads();
  for (int o = 128; o > 0; o >>= 1) {
    if (tid < o) {
      float v2 = redv[tid + o]; int i2 = redi[tid + o];
      if (v2 > redv[tid] || (v2 == redv[tid] && i2 < redi[tid])) { redv[tid] = v2; redi[tid] = i2; }
    }
    __syncthreads();
  }
  float ymax = redv[0]; int amax = redi[0]; __syncthreads();
  float e[4]; float s2 = 0.f;
#pragma unroll
  for (int i = 0; i < 4; ++i) { e[i] = expf(y[i] - ymax); s2 += e[i]; }
  red[tid] = s2; __syncthreads();
  for (int o = 128; o > 0; o >>= 1) { if (tid < o) red[tid] += red[tid + o]; __syncthreads(); }
  float inv = 1.f / red[0];
#pragma unroll
  for (int i = 0; i < 4; ++i) SPT[(size_t)t * MM + tid + 256 * i] = e[i] * inv;
  if (tid == 0) {
    int p = posi[t];
    int widx = wtbl[p * MM + amax];
    int wf = wflat[t];
    int avoid = (widx == wf) ? 1 : 0;
    avoidb[t] = avoid;
    out_word[t] = (float)(avoid ? 0 : widx);
    out_mask[t] = 1.0f;
    out_pri[t] = (p < 4) ? 1.0f : 0.0f;
    rowent[t] = enttot;
  }
}

// ---------------- K7: grouped emb GEMM out_emb[tok] = SPT[tok] @ Ptbl[p] ----------------
__global__ __launch_bounds__(256) void k_embgemm(const float* __restrict__ SPT,
    const float* __restrict__ Ptbl, const float* __restrict__ psrw,
    const int* __restrict__ counts, const int* __restrict__ offs,
    const int* __restrict__ idxlist, const int* __restrict__ avoidb,
    float* __restrict__ out_emb) {
  int p = blockIdx.y;
  int n = counts[p];
  int r0 = blockIdx.x * 64;
  if (r0 >= n) return;
  __shared__ float As[16][68];
  __shared__ float Bs[16][132];
  __shared__ int rows[64];
  int tid = threadIdx.x;
  if (tid < 64) rows[tid] = idxlist[offs[p] + ((r0 + tid) < n ? (r0 + tid) : 0)];
  __syncthreads();
  const float* P = Ptbl + (size_t)p * MM * EE;
  int tx = tid & 31, ty = tid >> 5;
  float acc[8][4] = {};
  for (int k0 = 0; k0 < MM; k0 += 16) {
    int r = tid >> 2, c = (tid & 3) * 4;
    float4 av = *(const float4*)(SPT + (size_t)rows[r] * MM + k0 + c);
    As[c + 0][r] = av.x; As[c + 1][r] = av.y; As[c + 2][r] = av.z; As[c + 3][r] = av.w;
    int r2 = tid >> 4;
    int c2 = (tid & 15) * 8;
    float4 b0 = make_float4(0.f, 0.f, 0.f, 0.f), b1 = make_float4(0.f, 0.f, 0.f, 0.f);
    if (c2 + 3 < EE) b0 = *(const float4*)(P + (size_t)(k0 + r2) * EE + c2);
    if (c2 + 7 < EE) b1 = *(const float4*)(P + (size_t)(k0 + r2) * EE + c2 + 4);
    *(float4*)(&Bs[r2][c2]) = b0;
    *(float4*)(&Bs[r2][c2 + 4]) = b1;
    __syncthreads();
#pragma unroll
    for (int kk = 0; kk < 16; ++kk) {
      float4 b4 = *(const float4*)(&Bs[kk][tx * 4]);
      float4 a0 = *(const float4*)(&As[kk][ty * 8]);
      float4 a1 = *(const float4*)(&As[kk][ty * 8 + 4]);
      float a[8] = {a0.x, a0.y, a0.z, a0.w, a1.x, a1.y, a1.z, a1.w};
#pragma unroll
      for (int ri = 0; ri < 8; ++ri) {
        acc[ri][0] += a[ri] * b4.x; acc[ri][1] += a[ri] * b4.y;
        acc[ri][2] += a[ri] * b4.z; acc[ri][3] += a[ri] * b4.w;
      }
    }
    __syncthreads();
  }
#pragma unroll
  for (int ri = 0; ri < 8; ++ri) {
    int r = ty * 8 + ri;
    if (r0 + r < n) {
      int tok = rows[r];
      int av = avoidb[tok];
#pragma unroll
      for (int j = 0; j < 4; ++j) {
        int col = tx * 4 + j;
        if (col < EE) {
          float v = av ? psrw[col] : acc[ri][j];
          out_emb[(size_t)tok * EE + col] = v;
        }
      }
    }
  }
}

// ---------------- K8: deterministic entropy-loss reduction ----------------
__global__ __launch_bounds__(256) void k_final(const float* __restrict__ rowent,
    const int* __restrict__ posi, const int* __restrict__ counts,
    float* __restrict__ out_loss) {
  __shared__ float red[256];
  int tid = threadIdx.x;
  float s = 0.f;
  for (int t = tid; t < TT; t += 256) {
    int p = posi[t];
    float denom = fmaxf((float)counts[p] * (float)MM, 1.0f);
    s += rowent[t] / denom;
  }
  red[tid] = s; __syncthreads();
  for (int o = 128; o > 0; o >>= 1) { if (tid < o) red[tid] += red[tid + o]; __syncthreads(); }
  if (tid == 0) out_loss[0] = -red[0] * 0.01f;
}

// ---------------- launcher ----------------
extern "C" void kernel_launch(void* const* d_in, const int* in_sizes, int n_in,
                              void* d_out, int out_size, void* d_ws, size_t ws_size,
                              hipStream_t stream) {
  const int*   inp_word = (const int*)d_in[0];
  const int*   inp_pos  = (const int*)d_in[1];
  const float* inp_mask = (const float*)d_in[2];
  const float* gum      = (const float*)d_in[3];
  const float* wemb     = (const float*)d_in[4];
  const float* pemb     = (const float*)d_in[5];
  const float* Wx_f     = (const float*)d_in[6];
  const float* Wh_f     = (const float*)d_in[7];
  const float* b_f      = (const float*)d_in[8];
  const float* Wx_b     = (const float*)d_in[9];
  const float* Wh_b     = (const float*)d_in[10];
  const float* b_b      = (const float*)d_in[11];
  const float* decW     = (const float*)d_in[12];
  const float* decb     = (const float*)d_in[13];
  const int*   wtbl     = (const int*)d_in[14];
  const float* psrw     = (const float*)d_in[15];

  float* out_word = (float*)d_out;
  float* out_emb  = out_word + TT;
  float* out_mask = out_emb + (size_t)TT * EE;
  float* out_pri  = out_mask + TT;
  float* out_loss = out_pri + TT;

  float* ws = (float*)d_ws;
  float* X      = ws;
  float* GXf    = X + (size_t)TT * DIN;
  float* GXb    = GXf + (size_t)TT * G4;
  float* ctxb   = GXb + (size_t)TT * G4;
  float* Hbuf   = ctxb + (size_t)TT * MM;
  float* rowent = Hbuf + 2 * 2 * BB * HH;
  int* avoidb   = (int*)(rowent + TT);
  int* counts   = avoidb + TT;
  int* offs     = counts + 16;
  int* idxlist  = offs + 32;
  float* Z    = GXf;   // reuse: GX dead after LSTM
  float* SPT  = Z;     // in-place row rewrite in k_softmax
  float* Ptbl = GXb;   // reuse

  k_embed<<<TT, 64, 0, stream>>>(inp_word, inp_pos, wemb, pemb, X);
  k_gemm_bias<<<dim3(G4 / 64, TT / 64), 256, 0, stream>>>(X, Wx_f, b_f, GXf, TT, G4, DIN);
  k_gemm_bias<<<dim3(G4 / 64, TT / 64), 256, 0, stream>>>(X, Wx_b, b_b, GXb, TT, G4, DIN);

  {
    void* args[] = {(void*)&Wh_f, (void*)&Wh_b, (void*)&GXf, (void*)&GXb,
                    (void*)&inp_mask, (void*)&Hbuf, (void*)&ctxb};
    hipLaunchCooperativeKernel((void*)k_lstm, dim3(256), dim3(512), args, 0, stream);
  }

  k_zero16<<<1, 64, 0, stream>>>(counts);
  k_count<<<TT / 256, 256, 0, stream>>>(inp_pos, counts);
  k_prefix<<<1, 64, 0, stream>>>(counts, offs);
  k_compact<<<NTAGS, 256, 0, stream>>>(inp_pos, offs, idxlist);
  k_ptbl<<<1024, 256, 0, stream>>>(wtbl, psrw, Ptbl);
  k_decgemm<<<dim3(MM / 64, TT / 64, NTAGS), 256, 0, stream>>>(ctxb, decW, decb, counts, offs, idxlist, Z);
  k_softmax<<<TT, 256, 0, stream>>>(Z, gum, inp_pos, inp_word, wtbl, SPT, rowent, avoidb,
                                    out_word, out_mask, out_pri);
  k_embgemm<<<dim3(TT / 64, NTAGS), 256, 0, stream>>>(SPT, Ptbl, psrw, counts, offs, idxlist,
                                                      avoidb, out_emb);
  k_final<<<1, 256, 0, stream>>>(rowent, inp_pos, counts, out_loss);
}